// Round 23
// baseline (234.519 us; speedup 1.0000x reference)
//
#include <hip/hip_runtime.h>
#include <math.h>

#define NPOS 131072  // 8*128*128 spatial positions per (b, channel)
#define GC 128       // gram chunks per (b,head); chunk = 1024 positions

typedef __attribute__((ext_vector_type(8))) short short8v;  // 8 bf16 (4 VGPR)
typedef __attribute__((ext_vector_type(4))) float f32x4;    // 4 fp32 acc

// Blocked layout for ALL intermediate tensors (r23): T[b][p>>6][c][p&63].
// Rationale: every pw variant r11-r22 ran at ~2.5-3 TB/s streaming 64
// channel-slices at 512KB stride; k_dw (single-channel-plane blocks) runs
// ~5.4 TB/s. Blocked tiles make pw writes / k_out reads fully contiguous.
__device__ __forceinline__ size_t baddr(int b, int c, int p) {
  return ((size_t)(b * 2048 + (p >> 6)) * 64 + c) * 64 + (p & 63);
}

// split fp32 -> bf16 hi + bf16 lo (x ~= hi + lo, lo residual ~2^-16 |x|)
__device__ __forceinline__ void bf16split(float x, unsigned short& hi, unsigned short& lo) {
  unsigned u = __float_as_uint(x);
  hi = (unsigned short)(u >> 16);
  float hif = __uint_as_float(u & 0xffff0000u);
  float l = x - hif;  // exact
  lo = (unsigned short)(__float_as_uint(l) >> 16);
}

// ---------------------------------------------------------------------------
// k_prep: split w_qkv [192 out][64 in] into A-fragment-layout bf16 hi/lo.
// ---------------------------------------------------------------------------
__global__ void k_prep(const float* __restrict__ w_qkv, unsigned short* __restrict__ whi,
                       unsigned short* __restrict__ wlo) {
  int idx = blockIdx.x * 256 + threadIdx.x;
  if (idx < 12288) {
    int j = idx & 7, l = (idx >> 3) & 63, ks = (idx >> 9) & 1, ot = (idx >> 10) & 3,
        g = idx >> 12;
    int out = ot * 16 + (l & 15);
    int k = ks * 32 + (l >> 4) * 8 + j;
    bf16split(w_qkv[(g * 64 + out) * 64 + k], whi[idx], wlo[idx]);
  }
}

// ---------------------------------------------------------------------------
// pw_mfma_core: MFMA compute from staged LDS x-tile into the bounce buffer.
// wave<->p-tile mapping (r22): B built once/wave, 24 MFMA.
// ---------------------------------------------------------------------------
__device__ __forceinline__ void pw_mfma_core(float (*xl)[66], const short8v (*ahi)[2],
                                             const short8v (*alo)[2], int tid) {
  const int lane = tid & 63;
  const int wid = tid >> 6;
  const int prow = lane & 15, kgrp = lane >> 4;
  const int pos = wid * 16 + prow;
  short8v bh[2], bl[2];
#pragma unroll
  for (int ks = 0; ks < 2; ++ks)
#pragma unroll
    for (int j = 0; j < 8; ++j) {
      unsigned short h, lo16;
      bf16split(xl[ks * 32 + kgrp * 8 + j][pos], h, lo16);
      bh[ks][j] = (short)h;
      bl[ks][j] = (short)lo16;
    }
  f32x4 D[4];
#pragma unroll
  for (int ot = 0; ot < 4; ++ot) {
    f32x4 d = {0.f, 0.f, 0.f, 0.f};
#pragma unroll
    for (int ks = 0; ks < 2; ++ks) {
      d = __builtin_amdgcn_mfma_f32_16x16x32_bf16(ahi[ot][ks], bh[ks], d, 0, 0, 0);
      d = __builtin_amdgcn_mfma_f32_16x16x32_bf16(ahi[ot][ks], bl[ks], d, 0, 0, 0);
      d = __builtin_amdgcn_mfma_f32_16x16x32_bf16(alo[ot][ks], bh[ks], d, 0, 0, 0);
    }
    D[ot] = d;
  }
  __syncthreads();  // all waves done reading xl; reuse as output tile
#pragma unroll
  for (int ot = 0; ot < 4; ++ot)
#pragma unroll
    for (int jj = 0; jj < 4; ++jj)
      xl[ot * 16 + kgrp * 4 + jj][pos] = D[ot][jj];
  __syncthreads();
}

// ---------------------------------------------------------------------------
// k_pw_mfma: pre_blk[tile] = W x x[tile]. x channel-major (given), output
// BLOCKED: one contiguous 16KB store range per workgroup.
// grid 4096 flat XCD-swizzled, block 256.
// ---------------------------------------------------------------------------
__global__ __launch_bounds__(256) void k_pw_mfma(const float* __restrict__ x,
                                                 const unsigned short* __restrict__ whi,
                                                 const unsigned short* __restrict__ wlo,
                                                 float* __restrict__ pre) {
  const int id = blockIdx.x;                   // 0..4095
  const int sid = (id & 7) * 512 + (id >> 3);  // XCD-contiguous (bijective)
  const int b = sid >> 11;                     // 0..1
  const int t = sid & 2047;                    // tile
  const int p0 = t * 64;
  const int lane = threadIdx.x & 63;
  const int tid = threadIdx.x;
  const int f4 = tid & 15;
  __shared__ __align__(16) float xl[64][66];
  short8v ahi[4][2], alo[4][2];
#pragma unroll
  for (int ot = 0; ot < 4; ++ot)
#pragma unroll
    for (int ks = 0; ks < 2; ++ks) {
      int fi = ((ot * 2 + ks) * 64 + lane) * 8;
      ahi[ot][ks] = *(const short8v*)&whi[fi];
      alo[ot][ks] = *(const short8v*)&wlo[fi];
    }
  const float* xb = x + ((size_t)b * 64) * NPOS + p0;
#pragma unroll
  for (int r = 0; r < 4; ++r) {
    int ch2 = (r * 256 + tid) >> 4;
    *(float4*)&xl[ch2][f4 * 4] = *(const float4*)&xb[(size_t)ch2 * NPOS + f4 * 4];
  }
  __syncthreads();
  pw_mfma_core(xl, ahi, alo, tid);
  // blocked writeout: fully contiguous 16KB per block
  float* go = pre + ((size_t)(b * 2048 + t) * 64) * 64;
#pragma unroll
  for (int r = 0; r < 4; ++r) {
    int idx = r * 256 + tid;
    *(float4*)&go[(size_t)idx * 4] = *(const float4*)&xl[idx >> 4][(idx & 15) * 4];
  }
}

// ---------------------------------------------------------------------------
// k_dw: depthwise 3x3x3 SAME, BLOCKED input and output. Flat grid 8192,
// XCD-swizzled. block (32, 8). Optional sum-of-squares partials -> nsq.
// ---------------------------------------------------------------------------
__global__ __launch_bounds__(256) void k_dw(const float* __restrict__ pre,
                                            const float* __restrict__ w_dw,
                                            float* __restrict__ conv,
                                            float* __restrict__ nsq, int g) {
  const int id = blockIdx.x;
  const int sid = (id & 7) * 1024 + (id >> 3);
  const int z = sid >> 6, r = sid & 63, by = r >> 2, bx = r & 3;
  const int b = z >> 6;
  const int c = z & 63;
  const int h0 = by * 8;
  const int w0 = bx * 32;
  __shared__ float t[10][10][40];
  __shared__ float red[4];
  const int tid = threadIdx.y * 32 + threadIdx.x;
  // stage: center float4 (within-tile aligned: w0%32==0, j*4<32), scalar edges
  for (int i = tid; i < 800; i += 256) {
    int j = i & 7, row = i >> 3;
    int h = row % 10, dpl = row / 10;
    int dd = dpl - 1, hh = h0 + h - 1;
    float4 v = make_float4(0.f, 0.f, 0.f, 0.f);
    if (dd >= 0 && dd < 8 && hh >= 0 && hh < 128) {
      int p = dd * 16384 + hh * 128 + w0 + j * 4;
      v = *(const float4*)&pre[baddr(b, c, p)];
    }
    *(float4*)&t[dpl][h][4 + j * 4] = v;
  }
  for (int i = tid; i < 200; i += 256) {
    int side = i & 1, row = i >> 1;
    int h = row % 10, dpl = row / 10;
    int dd = dpl - 1, hh = h0 + h - 1;
    int ww = side ? (w0 + 32) : (w0 - 1);
    float v = 0.f;
    if (dd >= 0 && dd < 8 && hh >= 0 && hh < 128 && ww >= 0 && ww < 128)
      v = pre[baddr(b, c, dd * 16384 + hh * 128 + ww)];
    t[dpl][h][side ? 36 : 3] = v;
  }
  float wk[27];
#pragma unroll
  for (int i = 0; i < 27; ++i) wk[i] = w_dw[(g * 64 + c) * 27 + i];
  __syncthreads();
  const int wl = threadIdx.x, hl = threadIdx.y;
  // d-rolling conv: 90 LDS reads, 216 FMA
  float acc[8];
#pragma unroll
  for (int d = 0; d < 8; ++d) acc[d] = 0.f;
#pragma unroll
  for (int dpl = 0; dpl < 10; ++dpl)
#pragma unroll
    for (int kh = 0; kh < 3; ++kh)
#pragma unroll
      for (int kw = 0; kw < 3; ++kw) {
        float f = t[dpl][hl + kh][3 + wl + kw];
#pragma unroll
        for (int kd = 0; kd < 3; ++kd) {
          const int d = dpl - kd;
          if (d >= 0 && d < 8)
            acc[d] = fmaf(f, wk[(kd * 3 + kh) * 3 + kw], acc[d]);
        }
      }
  float nsum = 0.f;
#pragma unroll
  for (int d = 0; d < 8; ++d) {
    int p = d * 16384 + (h0 + hl) * 128 + (w0 + wl);
    conv[baddr(b, c, p)] = acc[d];
    nsum = fmaf(acc[d], acc[d], nsum);
  }
  if (nsq) {
    const int lane = tid & 63, wv = tid >> 6;
    float v = nsum;
    v += __shfl_down(v, 32); v += __shfl_down(v, 16); v += __shfl_down(v, 8);
    v += __shfl_down(v, 4);  v += __shfl_down(v, 2);  v += __shfl_down(v, 1);
    if (lane == 0) red[wv] = v;
    __syncthreads();
    if (tid == 0) {
      const int blk = by * 4 + bx;
      nsq[((size_t)b * 64 + c) * 64 + blk] = red[0] + red[1] + red[2] + red[3];
    }
  }
}

// ---------------------------------------------------------------------------
// k_gramS: streaming Gram reduce on BLOCKED qconv/kconv. grid (GC, 16),
// block 256; butterfly-split reduction (63 shuffles).
// partialS[(bh*GC + chunk)*64 + c*8+e].
// ---------------------------------------------------------------------------
__global__ __launch_bounds__(256) void k_gramS(const float* __restrict__ qconv,
                                               const float* __restrict__ kconv,
                                               float* __restrict__ partialS) {
  const int chunk = blockIdx.x;   // 0..GC-1
  const int bh = blockIdx.y;      // 0..15
  const int b = bh >> 3, head = bh & 7;
  const int tid = threadIdx.x;
  const int c0 = head * 8;
  float S[64];
#pragma unroll
  for (int i = 0; i < 64; ++i) S[i] = 0.f;
#pragma unroll
  for (int it = 0; it < 4; ++it) {
    int p = chunk * 1024 + it * 256 + tid;
    size_t tbase = ((size_t)(b * 2048 + (p >> 6)) * 64) * 64 + (p & 63);
    float qv[8], kv[8];
#pragma unroll
    for (int c = 0; c < 8; ++c) qv[c] = qconv[tbase + (size_t)(c0 + c) * 64];
#pragma unroll
    for (int e = 0; e < 8; ++e) kv[e] = kconv[tbase + (size_t)(c0 + e) * 64];
#pragma unroll
    for (int c = 0; c < 8; ++c)
#pragma unroll
      for (int e = 0; e < 8; ++e) S[c * 8 + e] = fmaf(qv[c], kv[e], S[c * 8 + e]);
  }
#pragma unroll
  for (int i = 0; i < 64; ++i) asm volatile("" : "+v"(S[i]));  // keep S material

  const int lane = tid & 63, wv = tid >> 6;
#define BSTEP(src, dst, n, s)                                        \
  {                                                                  \
    const bool hi_ = (lane >> (s)) & 1;                              \
    _Pragma("unroll")                                                \
    for (int i_ = 0; i_ < (n); ++i_) {                               \
      float send_ = hi_ ? src[i_] : src[i_ + (n)];                   \
      float mine_ = hi_ ? src[i_ + (n)] : src[i_];                   \
      dst[i_] = mine_ + __shfl_xor(send_, 1 << (s));                 \
    }                                                                \
  }
  float v32[32], v16[16], v8[8], v4[4], v2[2], v1[1];
  BSTEP(S,   v32, 32, 0)
  BSTEP(v32, v16, 16, 1)
  BSTEP(v16, v8,   8, 2)
  BSTEP(v8,  v4,   4, 3)
  BSTEP(v4,  v2,   2, 4)
  BSTEP(v2,  v1,   1, 5)
#undef BSTEP
  const int idx = ((lane & 1) << 5) | ((lane & 2) << 3) | ((lane & 4) << 1) |
                  ((lane & 8) >> 1) | ((lane & 16) >> 3) | ((lane & 32) >> 5);
  __shared__ float red[4][64];
  red[wv][idx] = v1[0];
  __syncthreads();
  if (tid < 64) {
    float s = red[0][tid] + red[1][tid] + red[2][tid] + red[3][tid];
    partialS[((size_t)bh * GC + chunk) * 64 + tid] = s;
  }
}

// ---------------------------------------------------------------------------
// k_attn: reduce partialS + nqp/nkp, l2-normalize, temperature, softmax -> A.
// ---------------------------------------------------------------------------
__global__ void k_attn(const float* __restrict__ partialS, const float* __restrict__ nqp,
                       const float* __restrict__ nkp, const float* __restrict__ temp,
                       float* __restrict__ A) {
  const int bh = blockIdx.x;
  const int b = bh >> 3, head = bh & 7;
  const int tid = threadIdx.x;
  __shared__ float sums[80];
  if (tid < 64) {
    float s = 0.f;
    const float* pp = partialS + (size_t)bh * GC * 64 + tid;
    for (int j = 0; j < GC; ++j) s += pp[j * 64];
    sums[tid] = s;  // S[c*8+e]
  } else if (tid < 72) {
    const int e = tid - 64;
    float s = 0.f;
    const float* pp = nkp + ((size_t)b * 64 + head * 8 + e) * 64;
    for (int j = 0; j < 64; ++j) s += pp[j];
    sums[64 + e] = s;  // nk[e]
  } else if (tid < 80) {
    const int c = tid - 72;
    float s = 0.f;
    const float* pp = nqp + ((size_t)b * 64 + head * 8 + c) * 64;
    for (int j = 0; j < 64; ++j) s += pp[j];
    sums[72 + c] = s;  // nq[c]
  }
  __syncthreads();
  if (tid < 8) {
    const int c = tid;
    float tp = temp[head];
    float qd = fmaxf(sqrtf(sums[72 + c]), 1e-12f);
    float vals[8];
    float mx = -1e30f;
#pragma unroll
    for (int e = 0; e < 8; ++e) {
      float kd = fmaxf(sqrtf(sums[64 + e]), 1e-12f);
      vals[e] = sums[c * 8 + e] / (qd * kd) * tp;
      mx = fmaxf(mx, vals[e]);
    }
    float den = 0.f;
#pragma unroll
    for (int e = 0; e < 8; ++e) { vals[e] = expf(vals[e] - mx); den += vals[e]; }
#pragma unroll
    for (int e = 0; e < 8; ++e) A[bh * 64 + c * 8 + e] = vals[e] / den;
  }
}

// ---------------------------------------------------------------------------
// k_M: M_b = W_proj x blockdiag(softmax A_b), in A-fragment bf16 hi/lo layout.
// ---------------------------------------------------------------------------
__global__ void k_M(const float* __restrict__ w_proj, const float* __restrict__ A,
                    unsigned short* __restrict__ Mhi, unsigned short* __restrict__ Mlo) {
  const int b = blockIdx.x;
  for (int e = threadIdx.x; e < 4096; e += 256) {
    int j = e & 7, l = (e >> 3) & 63, ks = (e >> 9) & 1, ot = (e >> 10) & 3;
    int out = ot * 16 + (l & 15);
    int gch = ks * 32 + (l >> 4) * 8 + j;
    int hg = gch >> 3, jj = gch & 7;
    float s = 0.f;
#pragma unroll
    for (int i = 0; i < 8; ++i)
      s += w_proj[out * 64 + hg * 8 + i] * A[(b * 8 + hg) * 64 + i * 8 + jj];
    bf16split(s, Mhi[b * 4096 + e], Mlo[b * 4096 + e]);
  }
}

// ---------------------------------------------------------------------------
// k_out_mfma: out[b][o][p] = sum_g M_b[o][g] vconv_blk[g][p]. BLOCKED input
// (one contiguous 16KB read per block); channel-major output (required).
// grid 4096 flat XCD-swizzled, block 256.
// ---------------------------------------------------------------------------
__global__ __launch_bounds__(256) void k_out_mfma(const float* __restrict__ vconv,
                                                  const unsigned short* __restrict__ Mhi,
                                                  const unsigned short* __restrict__ Mlo,
                                                  float* __restrict__ out) {
  const int id = blockIdx.x;
  const int sid = (id & 7) * 512 + (id >> 3);
  const int b = sid >> 11;
  const int t = sid & 2047;
  const int p0 = t * 64;
  const int lane = threadIdx.x & 63;
  const int tid = threadIdx.x;
  const int f4 = tid & 15;
  __shared__ __align__(16) float xl[64][66];
  short8v ahi[4][2], alo[4][2];
#pragma unroll
  for (int ot = 0; ot < 4; ++ot)
#pragma unroll
    for (int ks = 0; ks < 2; ++ks) {
      int fi = b * 4096 + ((ot * 2 + ks) * 64 + lane) * 8;
      ahi[ot][ks] = *(const short8v*)&Mhi[fi];
      alo[ot][ks] = *(const short8v*)&Mlo[fi];
    }
  // blocked stage: fully contiguous 16KB per block
  const float* gi = vconv + ((size_t)(b * 2048 + t) * 64) * 64;
#pragma unroll
  for (int r = 0; r < 4; ++r) {
    int idx = r * 256 + tid;
    *(float4*)&xl[idx >> 4][(idx & 15) * 4] = *(const float4*)&gi[(size_t)idx * 4];
  }
  __syncthreads();
  pw_mfma_core(xl, ahi, alo, tid);
  // channel-major writeout (required output layout)
  float* ob = out + ((size_t)b * 64) * NPOS + p0;
#pragma unroll
  for (int r = 0; r < 4; ++r) {
    int row = (r * 256 + tid) >> 4;
    *(float4*)&ob[(size_t)row * NPOS + f4 * 4] = *(const float4*)&xl[row][f4 * 4];
  }
}

extern "C" void kernel_launch(void* const* d_in, const int* in_sizes, int n_in,
                              void* d_out, int out_size, void* d_ws, size_t ws_size,
                              hipStream_t stream) {
  const float* x      = (const float*)d_in[0];
  const float* w_qkv  = (const float*)d_in[1];
  const float* w_dw   = (const float*)d_in[2];
  const float* temp   = (const float*)d_in[3];
  const float* w_proj = (const float*)d_in[4];
  float* out = (float*)d_out;   // blocked pre staging per group; final output
  float* ws  = (float*)d_ws;

  // workspace layout — ~135 MB, produce->consume ordering (L3-resident chain)
  float* conv_buf = ws;                       // qconv, later vconv (blocked)
  float* kconv    = conv_buf + 16777216ull;   // blocked
  float* nqp      = kconv + 16777216ull;      // 8,192
  float* nkp      = nqp + 8192ull;            // 8,192
  float* partialS = nkp + 8192ull;            // 16*GC*64 = 131,072
  float* Abuf     = partialS + 131072ull;     // 1,024
  unsigned short* whi = (unsigned short*)(Abuf + 1024ull);  // 12,288 us
  unsigned short* wlo = whi + 12288ull;                     // 12,288 us
  unsigned short* Mhi = wlo + 12288ull;                     // 8,192 us
  unsigned short* Mlo = Mhi + 8192ull;                      // 8,192 us

  k_prep<<<48, 256, 0, stream>>>(w_qkv, whi, wlo);
  // q group: pointwise (MFMA, blocked out) -> d_out, depthwise -> conv_buf
  k_pw_mfma<<<4096, 256, 0, stream>>>(x, whi, wlo, out);
  k_dw<<<8192, dim3(32, 8), 0, stream>>>(out, w_dw, conv_buf, nqp, 0);
  // k group
  k_pw_mfma<<<4096, 256, 0, stream>>>(x, whi + 4096, wlo + 4096, out);
  k_dw<<<8192, dim3(32, 8), 0, stream>>>(out, w_dw, kconv, nkp, 1);
  // Gram + attention matrix + folded projection matrix
  k_gramS<<<dim3(GC, 16), 256, 0, stream>>>(conv_buf, kconv, partialS);
  k_attn<<<16, 128, 0, stream>>>(partialS, nqp, nkp, temp, Abuf);
  k_M<<<2, 256, 0, stream>>>(w_proj, Abuf, Mhi, Mlo);
  // v group: pointwise -> d_out (blocked), depthwise -> conv_buf, apply M
  k_pw_mfma<<<4096, 256, 0, stream>>>(x, whi + 8192, wlo + 8192, out);
  k_dw<<<8192, dim3(32, 8), 0, stream>>>(out, w_dw, conv_buf, nullptr, 2);
  k_out_mfma<<<4096, 256, 0, stream>>>(conv_buf, Mhi, Mlo, out);
}

// Round 24
// 232.437 us; speedup vs baseline: 1.0090x; 1.0090x over previous
//
#include <hip/hip_runtime.h>
#include <math.h>

#define NPOS 131072  // 8*128*128 spatial positions per (b, channel)
#define GC 128       // gram chunks per (b,head); chunk = 1024 positions

typedef __attribute__((ext_vector_type(8))) short short8v;  // 8 bf16 (4 VGPR)
typedef __attribute__((ext_vector_type(4))) float f32x4;    // 4 fp32 acc

// r24 layout for ALL intermediates: T[b][d][h][c][w], addr =
// (((b*8+d)*128+h)*64+c)*128 + w.  Every kernel's global access is >=512B
// contiguous (r23 evidence: >=512B-contiguous streams run ~5-6 TB/s; 128-256B
// segments at large stride run ~2.5 TB/s — pw/k_out fixed by blocking, but
// k_dw fell to 40us on 140B segments). Here: pw/k_out tiles are fully
// contiguous 32KB; dw stages ~520B row-chunks with zero w-halo loads.

// split fp32 -> bf16 hi + bf16 lo (x ~= hi + lo, lo residual ~2^-16 |x|)
__device__ __forceinline__ void bf16split(float x, unsigned short& hi, unsigned short& lo) {
  unsigned u = __float_as_uint(x);
  hi = (unsigned short)(u >> 16);
  float hif = __uint_as_float(u & 0xffff0000u);
  float l = x - hif;  // exact
  lo = (unsigned short)(__float_as_uint(l) >> 16);
}

// ---------------------------------------------------------------------------
// k_prep: split w_qkv [192 out][64 in] into A-fragment-layout bf16 hi/lo.
// ---------------------------------------------------------------------------
__global__ void k_prep(const float* __restrict__ w_qkv, unsigned short* __restrict__ whi,
                       unsigned short* __restrict__ wlo) {
  int idx = blockIdx.x * 256 + threadIdx.x;
  if (idx < 12288) {
    int j = idx & 7, l = (idx >> 3) & 63, ks = (idx >> 9) & 1, ot = (idx >> 10) & 3,
        g = idx >> 12;
    int out = ot * 16 + (l & 15);
    int k = ks * 32 + (l >> 4) * 8 + j;
    bf16split(w_qkv[(g * 64 + out) * 64 + k], whi[idx], wlo[idx]);
  }
}

// ---------------------------------------------------------------------------
// pw_mfma_core: MFMA over a staged [64ch][128pos] LDS tile. Each wave owns
// p-tiles {wid*16+prow, 64+wid*16+prow}; B built once per half (r22 mapping).
// Results bounced back into xl (as [out_ch][pos]) for contiguous writeout.
// ---------------------------------------------------------------------------
__device__ __forceinline__ void pw_mfma_core(float (*xl)[136], const short8v (*ahi)[2],
                                             const short8v (*alo)[2], int tid) {
  const int lane = tid & 63;
  const int wid = tid >> 6;
  const int prow = lane & 15, kgrp = lane >> 4;
  f32x4 D[2][4];
#pragma unroll
  for (int half = 0; half < 2; ++half) {
    const int pos = half * 64 + wid * 16 + prow;
    short8v bh[2], bl[2];
#pragma unroll
    for (int ks = 0; ks < 2; ++ks)
#pragma unroll
      for (int j = 0; j < 8; ++j) {
        unsigned short h, lo16;
        bf16split(xl[ks * 32 + kgrp * 8 + j][pos], h, lo16);
        bh[ks][j] = (short)h;
        bl[ks][j] = (short)lo16;
      }
#pragma unroll
    for (int ot = 0; ot < 4; ++ot) {
      f32x4 d = {0.f, 0.f, 0.f, 0.f};
#pragma unroll
      for (int ks = 0; ks < 2; ++ks) {
        d = __builtin_amdgcn_mfma_f32_16x16x32_bf16(ahi[ot][ks], bh[ks], d, 0, 0, 0);
        d = __builtin_amdgcn_mfma_f32_16x16x32_bf16(ahi[ot][ks], bl[ks], d, 0, 0, 0);
        d = __builtin_amdgcn_mfma_f32_16x16x32_bf16(alo[ot][ks], bh[ks], d, 0, 0, 0);
      }
      D[half][ot] = d;
    }
  }
  __syncthreads();  // all waves done reading xl; reuse as output tile
#pragma unroll
  for (int half = 0; half < 2; ++half) {
    const int pos = half * 64 + wid * 16 + prow;
#pragma unroll
    for (int ot = 0; ot < 4; ++ot)
#pragma unroll
      for (int jj = 0; jj < 4; ++jj)
        xl[ot * 16 + kgrp * 4 + jj][pos] = D[half][ot][jj];
  }
  __syncthreads();
}

// ---------------------------------------------------------------------------
// k_pw_mfma: one (b, d, h) full-w row tile (128 pos x 64 out-ch). x read
// channel-major (given); output fully CONTIGUOUS 32KB block in r24 layout.
// grid 2048 flat XCD-swizzled, block 256.
// ---------------------------------------------------------------------------
__global__ __launch_bounds__(256) void k_pw_mfma(const float* __restrict__ x,
                                                 const unsigned short* __restrict__ whi,
                                                 const unsigned short* __restrict__ wlo,
                                                 float* __restrict__ pre) {
  const int id = blockIdx.x;                   // 0..2047
  const int sid = (id & 7) * 256 + (id >> 3);  // XCD-contiguous (bijective)
  const int b = sid >> 10;
  const int t = sid & 1023;                    // d*128 + h
  const int p0 = t * 128;
  const int lane = threadIdx.x & 63;
  const int tid = threadIdx.x;
  __shared__ __align__(16) float xl[64][136];
  short8v ahi[4][2], alo[4][2];
#pragma unroll
  for (int ot = 0; ot < 4; ++ot)
#pragma unroll
    for (int ks = 0; ks < 2; ++ks) {
      int fi = ((ot * 2 + ks) * 64 + lane) * 8;
      ahi[ot][ks] = *(const short8v*)&whi[fi];
      alo[ot][ks] = *(const short8v*)&wlo[fi];
    }
  const float* xb = x + ((size_t)b * 64) * NPOS + p0;
#pragma unroll
  for (int r = 0; r < 8; ++r) {
    int idx = r * 256 + tid;           // 0..2047 float4
    int ch = idx >> 5, j = idx & 31;
    *(float4*)&xl[ch][j * 4] = *(const float4*)&xb[(size_t)ch * NPOS + j * 4];
  }
  __syncthreads();
  pw_mfma_core(xl, ahi, alo, tid);
  // contiguous 32KB writeout
  float* go = pre + (size_t)(b * 1024 + t) * 8192;
#pragma unroll
  for (int r = 0; r < 8; ++r) {
    int idx = r * 256 + tid;
    *(float4*)&go[(size_t)idx * 4] = *(const float4*)&xl[idx >> 5][(idx & 31) * 4];
  }
}

// ---------------------------------------------------------------------------
// k_dw: depthwise 3x3x3 SAME in r24 layout. Block = (b, c, hg): outputs
// 8d x 4h x 128w for one channel. Staging: 10 dpl x 6 h rows, each row is
// 8 x ~520B chunks inside ONE contiguous (h,c) 512B-strided row; w halo is
// boundary-zero (no loads). LDS t[10][6][136]. grid 4096 XCD-swizzled,
// block 256 (= 128w x 2h2). Optional sum-of-squares partials -> nsq[..*32+hg].
// ---------------------------------------------------------------------------
__global__ __launch_bounds__(256) void k_dw(const float* __restrict__ pre,
                                            const float* __restrict__ w_dw,
                                            float* __restrict__ conv,
                                            float* __restrict__ nsq, int g) {
  const int id = blockIdx.x;                   // 0..4095
  const int sid = (id & 7) * 512 + (id >> 3);  // XCD-contiguous
  const int b = sid >> 11;
  const int c = (sid >> 5) & 63;
  const int hg = sid & 31;
  const int h0 = hg * 4;
  __shared__ float t[10][6][136];
  __shared__ float red[4];
  const int tid = threadIdx.x;
  // zero the w-halo columns [3], [132], [133]
  for (int i = tid; i < 180; i += 256) {
    int row = i / 3, e = i - row * 3;
    int dpl = row / 6, h = row - dpl * 6;
    t[dpl][h][e == 0 ? 3 : 131 + e] = 0.f;
  }
  // stage center: 10dpl x 6h x 32 float4
  for (int i = tid; i < 1920; i += 256) {
    int dpl = i / 192, rem = i - dpl * 192;
    int h = rem >> 5, j = rem & 31;
    int dd = dpl - 1, hh = h0 + h - 1;
    float4 v = make_float4(0.f, 0.f, 0.f, 0.f);
    if (dd >= 0 && dd < 8 && hh >= 0 && hh < 128)
      v = *(const float4*)&pre[((size_t)((b * 1024 + dd * 128 + hh) * 64 + c)) * 128 + j * 4];
    *(float4*)&t[dpl][h][4 + j * 4] = v;
  }
  float wk[27];
#pragma unroll
  for (int i = 0; i < 27; ++i) wk[i] = w_dw[(g * 64 + c) * 27 + i];
  __syncthreads();
  const int w = tid & 127, h2 = tid >> 7;   // thread = (w, h2); h_local = h2, h2+2
  float nsum = 0.f;
#pragma unroll
  for (int hh2 = 0; hh2 < 2; ++hh2) {
    const int hl = h2 + hh2 * 2;
    float acc[8];
#pragma unroll
    for (int d = 0; d < 8; ++d) acc[d] = 0.f;
#pragma unroll
    for (int dpl = 0; dpl < 10; ++dpl)
#pragma unroll
      for (int kh = 0; kh < 3; ++kh)
#pragma unroll
        for (int kw = 0; kw < 3; ++kw) {
          float f = t[dpl][hl + kh][3 + w + kw];
#pragma unroll
          for (int kd = 0; kd < 3; ++kd) {
            const int d = dpl - kd;
            if (d >= 0 && d < 8)
              acc[d] = fmaf(f, wk[(kd * 3 + kh) * 3 + kw], acc[d]);
          }
        }
#pragma unroll
    for (int d = 0; d < 8; ++d) {
      conv[((size_t)((b * 1024 + d * 128 + h0 + hl) * 64 + c)) * 128 + w] = acc[d];
      nsum = fmaf(acc[d], acc[d], nsum);
    }
  }
  if (nsq) {
    const int lane = tid & 63, wv = tid >> 6;
    float v = nsum;
    v += __shfl_down(v, 32); v += __shfl_down(v, 16); v += __shfl_down(v, 8);
    v += __shfl_down(v, 4);  v += __shfl_down(v, 2);  v += __shfl_down(v, 1);
    if (lane == 0) red[wv] = v;
    __syncthreads();
    if (tid == 0)
      nsq[((size_t)b * 64 + c) * 32 + hg] = red[0] + red[1] + red[2] + red[3];
  }
}

// ---------------------------------------------------------------------------
// k_gramS: streaming Gram reduce in r24 layout (8 channel loads at 512B
// stride, lanes w-contiguous). grid (GC, 16), block 256; butterfly-split
// reduction. partialS[(bh*GC + chunk)*64 + c*8+e].
// ---------------------------------------------------------------------------
__global__ __launch_bounds__(256) void k_gramS(const float* __restrict__ qconv,
                                               const float* __restrict__ kconv,
                                               float* __restrict__ partialS) {
  const int chunk = blockIdx.x;   // 0..GC-1
  const int bh = blockIdx.y;      // 0..15
  const int b = bh >> 3, head = bh & 7;
  const int tid = threadIdx.x;
  const int c0 = head * 8;
  float S[64];
#pragma unroll
  for (int i = 0; i < 64; ++i) S[i] = 0.f;
#pragma unroll
  for (int it = 0; it < 4; ++it) {
    int p = chunk * 1024 + it * 256 + tid;
    int d = p >> 14, h = (p >> 7) & 127, w = p & 127;
    size_t base = ((size_t)((b * 1024 + d * 128 + h) * 64 + c0)) * 128 + w;
    float qv[8], kv[8];
#pragma unroll
    for (int c = 0; c < 8; ++c) qv[c] = qconv[base + (size_t)c * 128];
#pragma unroll
    for (int e = 0; e < 8; ++e) kv[e] = kconv[base + (size_t)e * 128];
#pragma unroll
    for (int c = 0; c < 8; ++c)
#pragma unroll
      for (int e = 0; e < 8; ++e) S[c * 8 + e] = fmaf(qv[c], kv[e], S[c * 8 + e]);
  }
#pragma unroll
  for (int i = 0; i < 64; ++i) asm volatile("" : "+v"(S[i]));  // keep S material

  const int lane = tid & 63, wv = tid >> 6;
#define BSTEP(src, dst, n, s)                                        \
  {                                                                  \
    const bool hi_ = (lane >> (s)) & 1;                              \
    _Pragma("unroll")                                                \
    for (int i_ = 0; i_ < (n); ++i_) {                               \
      float send_ = hi_ ? src[i_] : src[i_ + (n)];                   \
      float mine_ = hi_ ? src[i_ + (n)] : src[i_];                   \
      dst[i_] = mine_ + __shfl_xor(send_, 1 << (s));                 \
    }                                                                \
  }
  float v32[32], v16[16], v8[8], v4[4], v2[2], v1[1];
  BSTEP(S,   v32, 32, 0)
  BSTEP(v32, v16, 16, 1)
  BSTEP(v16, v8,   8, 2)
  BSTEP(v8,  v4,   4, 3)
  BSTEP(v4,  v2,   2, 4)
  BSTEP(v2,  v1,   1, 5)
#undef BSTEP
  const int idx = ((lane & 1) << 5) | ((lane & 2) << 3) | ((lane & 4) << 1) |
                  ((lane & 8) >> 1) | ((lane & 16) >> 3) | ((lane & 32) >> 5);
  __shared__ float red[4][64];
  red[wv][idx] = v1[0];
  __syncthreads();
  if (tid < 64) {
    float s = red[0][tid] + red[1][tid] + red[2][tid] + red[3][tid];
    partialS[((size_t)bh * GC + chunk) * 64 + tid] = s;
  }
}

// ---------------------------------------------------------------------------
// k_attn: reduce partialS (GC chunks) + nqp/nkp (32 hg blocks), l2-normalize,
// temperature, softmax -> A[bh][c][e]. grid 16, block 128.
// ---------------------------------------------------------------------------
__global__ void k_attn(const float* __restrict__ partialS, const float* __restrict__ nqp,
                       const float* __restrict__ nkp, const float* __restrict__ temp,
                       float* __restrict__ A) {
  const int bh = blockIdx.x;
  const int b = bh >> 3, head = bh & 7;
  const int tid = threadIdx.x;
  __shared__ float sums[80];
  if (tid < 64) {
    float s = 0.f;
    const float* pp = partialS + (size_t)bh * GC * 64 + tid;
    for (int j = 0; j < GC; ++j) s += pp[j * 64];
    sums[tid] = s;  // S[c*8+e]
  } else if (tid < 72) {
    const int e = tid - 64;
    float s = 0.f;
    const float* pp = nkp + ((size_t)b * 64 + head * 8 + e) * 32;
    for (int j = 0; j < 32; ++j) s += pp[j];
    sums[64 + e] = s;  // nk[e]
  } else if (tid < 80) {
    const int c = tid - 72;
    float s = 0.f;
    const float* pp = nqp + ((size_t)b * 64 + head * 8 + c) * 32;
    for (int j = 0; j < 32; ++j) s += pp[j];
    sums[72 + c] = s;  // nq[c]
  }
  __syncthreads();
  if (tid < 8) {
    const int c = tid;
    float tp = temp[head];
    float qd = fmaxf(sqrtf(sums[72 + c]), 1e-12f);
    float vals[8];
    float mx = -1e30f;
#pragma unroll
    for (int e = 0; e < 8; ++e) {
      float kd = fmaxf(sqrtf(sums[64 + e]), 1e-12f);
      vals[e] = sums[c * 8 + e] / (qd * kd) * tp;
      mx = fmaxf(mx, vals[e]);
    }
    float den = 0.f;
#pragma unroll
    for (int e = 0; e < 8; ++e) { vals[e] = expf(vals[e] - mx); den += vals[e]; }
#pragma unroll
    for (int e = 0; e < 8; ++e) A[bh * 64 + c * 8 + e] = vals[e] / den;
  }
}

// ---------------------------------------------------------------------------
// k_M: M_b = W_proj x blockdiag(softmax A_b), in A-fragment bf16 hi/lo layout.
// ---------------------------------------------------------------------------
__global__ void k_M(const float* __restrict__ w_proj, const float* __restrict__ A,
                    unsigned short* __restrict__ Mhi, unsigned short* __restrict__ Mlo) {
  const int b = blockIdx.x;
  for (int e = threadIdx.x; e < 4096; e += 256) {
    int j = e & 7, l = (e >> 3) & 63, ks = (e >> 9) & 1, ot = (e >> 10) & 3;
    int out = ot * 16 + (l & 15);
    int gch = ks * 32 + (l >> 4) * 8 + j;
    int hg = gch >> 3, jj = gch & 7;
    float s = 0.f;
#pragma unroll
    for (int i = 0; i < 8; ++i)
      s += w_proj[out * 64 + hg * 8 + i] * A[(b * 8 + hg) * 64 + i * 8 + jj];
    bf16split(s, Mhi[b * 4096 + e], Mlo[b * 4096 + e]);
  }
}

// ---------------------------------------------------------------------------
// k_out_mfma: out = M_b x vconv. vconv read fully CONTIGUOUS (32KB/block,
// r24 layout); out written channel-major (required). grid 2048 XCD-swizzled.
// ---------------------------------------------------------------------------
__global__ __launch_bounds__(256) void k_out_mfma(const float* __restrict__ vconv,
                                                  const unsigned short* __restrict__ Mhi,
                                                  const unsigned short* __restrict__ Mlo,
                                                  float* __restrict__ out) {
  const int id = blockIdx.x;
  const int sid = (id & 7) * 256 + (id >> 3);
  const int b = sid >> 10;
  const int t = sid & 1023;
  const int p0 = t * 128;
  const int lane = threadIdx.x & 63;
  const int tid = threadIdx.x;
  __shared__ __align__(16) float xl[64][136];
  short8v ahi[4][2], alo[4][2];
#pragma unroll
  for (int ot = 0; ot < 4; ++ot)
#pragma unroll
    for (int ks = 0; ks < 2; ++ks) {
      int fi = b * 4096 + ((ot * 2 + ks) * 64 + lane) * 8;
      ahi[ot][ks] = *(const short8v*)&Mhi[fi];
      alo[ot][ks] = *(const short8v*)&Mlo[fi];
    }
  const float* gi = vconv + (size_t)(b * 1024 + t) * 8192;
#pragma unroll
  for (int r = 0; r < 8; ++r) {
    int idx = r * 256 + tid;
    *(float4*)&xl[idx >> 5][(idx & 31) * 4] = *(const float4*)&gi[(size_t)idx * 4];
  }
  __syncthreads();
  pw_mfma_core(xl, ahi, alo, tid);
  float* ob = out + ((size_t)b * 64) * NPOS + p0;
#pragma unroll
  for (int r = 0; r < 8; ++r) {
    int idx = r * 256 + tid;
    int o = idx >> 5, j = idx & 31;
    *(float4*)&ob[(size_t)o * NPOS + j * 4] = *(const float4*)&xl[o][j * 4];
  }
}

extern "C" void kernel_launch(void* const* d_in, const int* in_sizes, int n_in,
                              void* d_out, int out_size, void* d_ws, size_t ws_size,
                              hipStream_t stream) {
  const float* x      = (const float*)d_in[0];
  const float* w_qkv  = (const float*)d_in[1];
  const float* w_dw   = (const float*)d_in[2];
  const float* temp   = (const float*)d_in[3];
  const float* w_proj = (const float*)d_in[4];
  float* out = (float*)d_out;   // r24-layout pre staging per group; final output
  float* ws  = (float*)d_ws;

  // workspace layout — ~135 MB, produce->consume ordering (L3-resident chain)
  float* conv_buf = ws;                       // qconv, later vconv (r24 layout)
  float* kconv    = conv_buf + 16777216ull;   // r24 layout
  float* nqp      = kconv + 16777216ull;      // 2*64*32 = 4,096 (alloc 8,192)
  float* nkp      = nqp + 8192ull;            // 8,192
  float* partialS = nkp + 8192ull;            // 16*GC*64 = 131,072
  float* Abuf     = partialS + 131072ull;     // 1,024
  unsigned short* whi = (unsigned short*)(Abuf + 1024ull);  // 12,288 us
  unsigned short* wlo = whi + 12288ull;                     // 12,288 us
  unsigned short* Mhi = wlo + 12288ull;                     // 8,192 us
  unsigned short* Mlo = Mhi + 8192ull;                      // 8,192 us

  k_prep<<<48, 256, 0, stream>>>(w_qkv, whi, wlo);
  // q group: pointwise (MFMA, r24 out) -> d_out, depthwise -> conv_buf (+nq)
  k_pw_mfma<<<2048, 256, 0, stream>>>(x, whi, wlo, out);
  k_dw<<<4096, 256, 0, stream>>>(out, w_dw, conv_buf, nqp, 0);
  // k group
  k_pw_mfma<<<2048, 256, 0, stream>>>(x, whi + 4096, wlo + 4096, out);
  k_dw<<<4096, 256, 0, stream>>>(out, w_dw, kconv, nkp, 1);
  // Gram + attention matrix + folded projection matrix
  k_gramS<<<dim3(GC, 16), 256, 0, stream>>>(conv_buf, kconv, partialS);
  k_attn<<<16, 128, 0, stream>>>(partialS, nqp, nkp, temp, Abuf);
  k_M<<<2, 256, 0, stream>>>(w_proj, Abuf, Mhi, Mlo);
  // v group: pointwise -> d_out, depthwise -> conv_buf, apply M -> d_out
  k_pw_mfma<<<2048, 256, 0, stream>>>(x, whi + 8192, wlo + 8192, out);
  k_dw<<<4096, 256, 0, stream>>>(out, w_dw, conv_buf, nullptr, 2);
  k_out_mfma<<<2048, 256, 0, stream>>>(conv_buf, Mhi, Mlo, out);
}